// Round 7
// baseline (168.039 us; speedup 1.0000x reference)
//
#include <hip/hip_runtime.h>
#include <math.h>

// Problem constants (fixed by setup_inputs)
#define BB 4
#define SS 512
#define EE 512
#define NH 8
#define HD 64
#define NC 128
#define NTAB 4096  // table intervals over sa in [-0.4, 0.4]

typedef _Float16 f16x8 __attribute__((ext_vector_type(8)));
typedef float f32x4 __attribute__((ext_vector_type(4)));

struct HL { _Float16 h, l; };

__device__ __forceinline__ float clampf(float v, float lo, float hi) {
  return fminf(fmaxf(v, lo), hi);
}
__device__ __forceinline__ HL split16(float x) {
  HL r;
  r.h = (_Float16)x;
  r.l = (_Float16)(x - (float)r.h);
  return r;
}

__device__ __forceinline__ float waveRedSum(float v) {
#pragma unroll
  for (int o = 32; o; o >>= 1) v += __shfl_xor(v, o);
  return v;
}
__device__ __forceinline__ float waveRedMax(float v) {
#pragma unroll
  for (int o = 32; o; o >>= 1) v = fmaxf(v, __shfl_xor(v, o));
  return v;
}
// blockDim.x == 256 (4 waves) assumed
__device__ __forceinline__ float blockRedSum(float v, float* red) {
  int tid = threadIdx.x;
  v = waveRedSum(v);
  __syncthreads();
  if ((tid & 63) == 0) red[tid >> 6] = v;
  __syncthreads();
  return red[0] + red[1] + red[2] + red[3];
}
__device__ __forceinline__ float blockRedMax(float v, float* red) {
  int tid = threadIdx.x;
  v = waveRedMax(v);
  __syncthreads();
  if ((tid & 63) == 0) red[tid >> 6] = v;
  __syncthreads();
  return fmaxf(fmaxf(red[0], red[1]), fmaxf(red[2], red[3]));
}

// ---------------------------------------------------------------------------
// K_prep: transpose+split the 4 weight matrices (blocks 0..255) and split
// x -> f16-high (blocks 256..287).
__global__ __launch_bounds__(256) void k_prep(
    const float* __restrict__ Wq, const float* __restrict__ Wk,
    const float* __restrict__ Wv, const float* __restrict__ Wo,
    const float* __restrict__ x,
    _Float16* __restrict__ Wth, _Float16* __restrict__ Wtl,
    _Float16* __restrict__ xh) {
  const int j = blockIdx.x;
  const int tid = threadIdx.x;
  if (j >= 256) {
    const int rb = (j - 256) * 64;
    const int r = tid >> 2;
    const int c0 = (tid & 3) * 128;
    const float* src = x + (size_t)(rb + r) * EE + c0;
    _Float16* dst = xh + (size_t)(rb + r) * EE + c0;
#pragma unroll
    for (int c = 0; c < 128; c += 8) {
      float4 a = *(const float4*)(src + c);
      float4 b = *(const float4*)(src + c + 4);
      f16x8 h;
      h[0] = (_Float16)a.x; h[1] = (_Float16)a.y;
      h[2] = (_Float16)a.z; h[3] = (_Float16)a.w;
      h[4] = (_Float16)b.x; h[5] = (_Float16)b.y;
      h[6] = (_Float16)b.z; h[7] = (_Float16)b.w;
      *(f16x8*)(dst + c) = h;
    }
    return;
  }
  const int z = j >> 6;
  const int rem = j & 63;
  const int k0 = (rem & 7) * 64, n0 = (rem >> 3) * 64;
  const float* W = (z == 0) ? Wq : (z == 1) ? Wk : (z == 2) ? Wv : Wo;
  __shared__ float Tt[64][68];
  const int r = tid >> 2, c = (tid & 3) * 16;
#pragma unroll
  for (int jj = 0; jj < 16; jj += 4)
    *(float4*)&Tt[r][c + jj] =
        *(const float4*)(W + (size_t)(k0 + r) * EE + n0 + c + jj);
  __syncthreads();
  f16x8 h0, l0, h1, l1;
#pragma unroll
  for (int jj = 0; jj < 8; ++jj) {
    HL r0 = split16(Tt[c + jj][r]);
    HL r1 = split16(Tt[c + 8 + jj][r]);
    h0[jj] = r0.h; l0[jj] = r0.l;
    h1[jj] = r1.h; l1[jj] = r1.l;
  }
  _Float16* dh = Wth + ((size_t)z * EE + n0 + r) * EE + k0 + c;
  _Float16* dl = Wtl + ((size_t)z * EE + n0 + r) * EE + k0 + c;
  *(f16x8*)dh = h0;
  *(f16x8*)(dh + 8) = h1;
  *(f16x8*)dl = l0;
  *(f16x8*)(dl + 8) = l1;
}

// ---------------------------------------------------------------------------
// K_qkv: LDS-staged 2-term f16 MFMA GEMM (xh*Wh + xh*Wl). q pre-scaled by
// 0.125, high-only; k split h/l; V transposed split [bh][d][si].
__global__ __launch_bounds__(256) void k_qkv_mfma(
    const _Float16* __restrict__ xh,
    const _Float16* __restrict__ Wth, const _Float16* __restrict__ Wtl,
    const float* __restrict__ bq, const float* __restrict__ bk,
    const float* __restrict__ bv, const float* __restrict__ w1,
    const float* __restrict__ b1, const float* __restrict__ w2,
    const float* __restrict__ b2, float* __restrict__ T,
    _Float16* __restrict__ qh,
    _Float16* __restrict__ kh, _Float16* __restrict__ kl,
    _Float16* __restrict__ vth, _Float16* __restrict__ vtl) {
  const int which = blockIdx.z;
  const int tid = threadIdx.x;
  const int wave = tid >> 6, lane = tid & 63;
  const int quad = lane >> 4, l16 = lane & 15;
  const int m0 = blockIdx.y * 64;
  const int n0 = blockIdx.x * 64;
  const _Float16* Bh = Wth + (size_t)which * EE * EE;
  const _Float16* Bl = Wtl + (size_t)which * EE * EE;

  __shared__ __align__(16) char smpool[27648];
  _Float16(*LAh)[72] = (_Float16(*)[72])(smpool);
  _Float16(*LBh)[72] = (_Float16(*)[72])(smpool + 9216);
  _Float16(*LBl)[72] = (_Float16(*)[72])(smpool + 18432);
  float(*TR)[68] = (float(*)[68])(smpool);  // reused for V transpose

  const int sr0 = tid >> 3, sc0 = (tid & 7) * 8;
  const int sr1 = sr0 + 32;

  f16x8 rA0h = *(const f16x8*)(xh + (size_t)(m0 + sr0) * EE + sc0);
  f16x8 rA1h = *(const f16x8*)(xh + (size_t)(m0 + sr1) * EE + sc0);
  f16x8 rB0h = *(const f16x8*)(Bh + (size_t)(n0 + sr0) * EE + sc0);
  f16x8 rB0l = *(const f16x8*)(Bl + (size_t)(n0 + sr0) * EE + sc0);
  f16x8 rB1h = *(const f16x8*)(Bh + (size_t)(n0 + sr1) * EE + sc0);
  f16x8 rB1l = *(const f16x8*)(Bl + (size_t)(n0 + sr1) * EE + sc0);

  f32x4 acc[4] = {};
  for (int k0 = 0; k0 < EE; k0 += 64) {
    if (k0) __syncthreads();
    *(f16x8*)&LAh[sr0][sc0] = rA0h;
    *(f16x8*)&LAh[sr1][sc0] = rA1h;
    *(f16x8*)&LBh[sr0][sc0] = rB0h;
    *(f16x8*)&LBl[sr0][sc0] = rB0l;
    *(f16x8*)&LBh[sr1][sc0] = rB1h;
    *(f16x8*)&LBl[sr1][sc0] = rB1l;
    __syncthreads();
    if (k0 + 64 < EE) {
      const int kn = k0 + 64;
      rA0h = *(const f16x8*)(xh + (size_t)(m0 + sr0) * EE + kn + sc0);
      rA1h = *(const f16x8*)(xh + (size_t)(m0 + sr1) * EE + kn + sc0);
      rB0h = *(const f16x8*)(Bh + (size_t)(n0 + sr0) * EE + kn + sc0);
      rB0l = *(const f16x8*)(Bl + (size_t)(n0 + sr0) * EE + kn + sc0);
      rB1h = *(const f16x8*)(Bh + (size_t)(n0 + sr1) * EE + kn + sc0);
      rB1l = *(const f16x8*)(Bl + (size_t)(n0 + sr1) * EE + kn + sc0);
    }
#pragma unroll
    for (int kk = 0; kk < 64; kk += 32) {
      f16x8 ah = *(const f16x8*)&LAh[wave * 16 + l16][kk + quad * 8];
#pragma unroll
      for (int nt = 0; nt < 4; ++nt) {
        f16x8 bhf = *(const f16x8*)&LBh[nt * 16 + l16][kk + quad * 8];
        f16x8 blf = *(const f16x8*)&LBl[nt * 16 + l16][kk + quad * 8];
        acc[nt] = __builtin_amdgcn_mfma_f32_16x16x32_f16(ah, bhf, acc[nt], 0, 0, 0);
        acc[nt] = __builtin_amdgcn_mfma_f32_16x16x32_f16(ah, blf, acc[nt], 0, 0, 0);
      }
    }
  }
  const float* bias = (which == 0) ? bq : (which == 1) ? bk : bv;
  if (which == 2) {
    __syncthreads();
#pragma unroll
    for (int nt = 0; nt < 4; ++nt) {
      const int dcol = nt * 16 + l16;
      const float bb = bias[n0 + nt * 16 + l16];
#pragma unroll
      for (int r = 0; r < 4; ++r)
        TR[dcol][wave * 16 + quad * 4 + r] = acc[nt][r] + bb;
    }
    __syncthreads();
    const int d = tid >> 2, cc = (tid & 3) * 16;
    const int bh = (m0 >> 9) * NH + (n0 >> 6);
    const int si0 = m0 & 511;
    f16x8 h0, l0, h1, l1;
#pragma unroll
    for (int jj = 0; jj < 8; ++jj) {
      HL r0 = split16(TR[d][cc + jj]);
      HL r1 = split16(TR[d][cc + 8 + jj]);
      h0[jj] = r0.h; l0[jj] = r0.l;
      h1[jj] = r1.h; l1[jj] = r1.l;
    }
    _Float16* dh = vth + ((size_t)bh * HD + d) * SS + si0 + cc;
    _Float16* dl = vtl + ((size_t)bh * HD + d) * SS + si0 + cc;
    *(f16x8*)dh = h0;
    *(f16x8*)(dh + 8) = h1;
    *(f16x8*)dl = l0;
    *(f16x8*)(dl + 8) = l1;
  } else {
    const float postscale = (which == 0) ? 0.125f : 1.0f;
    const int mbase = m0 + wave * 16 + quad * 4;
#pragma unroll
    for (int nt = 0; nt < 4; ++nt) {
      const int col = n0 + nt * 16 + l16;
      const float bb = bias[col];
#pragma unroll
      for (int r = 0; r < 4; ++r) {
        const size_t idx = (size_t)(mbase + r) * EE + col;
        const float val = (acc[nt][r] + bb) * postscale;
        if (which == 0) {
          qh[idx] = (_Float16)val;
        } else {
          HL sp = split16(val);
          kh[idx] = sp.h;
          kl[idx] = sp.l;
        }
      }
    }
    // sigmoid-table side job
    if (which == 0 && blockIdx.x == 0 && blockIdx.y < 17) {
      int idx = blockIdx.y * 256 + tid;
      if (idx <= NTAB) {
        float sa = -0.4f + (float)idx * (0.8f / (float)NTAB);
        float ap = 0.f;
#pragma unroll 4
        for (int c = 0; c < NC; ++c) {
          float h = fminf(fmaxf(sa * w1[c] + b1[c], 0.f), 5.f);
          ap += h * w2[c];
        }
        ap = clampf(ap + b2[0], -5.f, 5.f);
        float tay = clampf(1.0f + 0.05f * (ap * 50.0f), 0.5f, 1.5f);
        T[idx] = 1.0f / (1.0f + expf(-tay));
      }
    }
  }
}

// ---------------------------------------------------------------------------
// K_ma: ma = 0.125 * Q_flat @ K_flat^T (K=512), 2-term, f16 output.
__global__ __launch_bounds__(256) void k_ma_mfma(
    const _Float16* __restrict__ qh,
    const _Float16* __restrict__ kh, const _Float16* __restrict__ kl,
    _Float16* __restrict__ ma) {
  const int tid = threadIdx.x;
  const int wave = tid >> 6, lane = tid & 63;
  const int quad = lane >> 4, l16 = lane & 15;
  const int m0 = blockIdx.y * 64;
  const int n0 = blockIdx.x * 64;
  const _Float16* Bh = kh + (size_t)(m0 >> 9) * SS * EE;
  const _Float16* Bl = kl + (size_t)(m0 >> 9) * SS * EE;

  __shared__ _Float16 LAh[64][72], LBh[64][72], LBl[64][72];

  const int sr0 = tid >> 3, sc0 = (tid & 7) * 8;
  const int sr1 = sr0 + 32;

  f16x8 rA0h = *(const f16x8*)(qh + (size_t)(m0 + sr0) * EE + sc0);
  f16x8 rB0h = *(const f16x8*)(Bh + (size_t)(n0 + sr0) * EE + sc0);
  f16x8 rB0l = *(const f16x8*)(Bl + (size_t)(n0 + sr0) * EE + sc0);
  f16x8 rA1h = *(const f16x8*)(qh + (size_t)(m0 + sr1) * EE + sc0);
  f16x8 rB1h = *(const f16x8*)(Bh + (size_t)(n0 + sr1) * EE + sc0);
  f16x8 rB1l = *(const f16x8*)(Bl + (size_t)(n0 + sr1) * EE + sc0);

  f32x4 acc[4] = {};
  for (int k0 = 0; k0 < EE; k0 += 64) {
    if (k0) __syncthreads();
    *(f16x8*)&LAh[sr0][sc0] = rA0h;
    *(f16x8*)&LBh[sr0][sc0] = rB0h;
    *(f16x8*)&LBl[sr0][sc0] = rB0l;
    *(f16x8*)&LAh[sr1][sc0] = rA1h;
    *(f16x8*)&LBh[sr1][sc0] = rB1h;
    *(f16x8*)&LBl[sr1][sc0] = rB1l;
    __syncthreads();
    if (k0 + 64 < EE) {
      const int kn = k0 + 64;
      rA0h = *(const f16x8*)(qh + (size_t)(m0 + sr0) * EE + kn + sc0);
      rB0h = *(const f16x8*)(Bh + (size_t)(n0 + sr0) * EE + kn + sc0);
      rB0l = *(const f16x8*)(Bl + (size_t)(n0 + sr0) * EE + kn + sc0);
      rA1h = *(const f16x8*)(qh + (size_t)(m0 + sr1) * EE + kn + sc0);
      rB1h = *(const f16x8*)(Bh + (size_t)(n0 + sr1) * EE + kn + sc0);
      rB1l = *(const f16x8*)(Bl + (size_t)(n0 + sr1) * EE + kn + sc0);
    }
#pragma unroll
    for (int kk = 0; kk < 64; kk += 32) {
      f16x8 ah = *(const f16x8*)&LAh[wave * 16 + l16][kk + quad * 8];
#pragma unroll
      for (int nt = 0; nt < 4; ++nt) {
        f16x8 bhf = *(const f16x8*)&LBh[nt * 16 + l16][kk + quad * 8];
        f16x8 blf = *(const f16x8*)&LBl[nt * 16 + l16][kk + quad * 8];
        acc[nt] = __builtin_amdgcn_mfma_f32_16x16x32_f16(ah, bhf, acc[nt], 0, 0, 0);
        acc[nt] = __builtin_amdgcn_mfma_f32_16x16x32_f16(ah, blf, acc[nt], 0, 0, 0);
      }
    }
  }
  const int mbase = m0 + wave * 16 + quad * 4;
#pragma unroll
  for (int nt = 0; nt < 4; ++nt) {
    const int col = n0 + nt * 16 + l16;
#pragma unroll
    for (int r = 0; r < 4; ++r) {
      ma[(size_t)(mbase + r) * SS + col] = (_Float16)(acc[nt][r] * 0.125f);
    }
  }
}

// ---------------------------------------------------------------------------
// K_rowstat: per-row autopoietic transform from f16 ma. One wave per row.
__global__ __launch_bounds__(256) void k_rowstat(
    const _Float16* __restrict__ ma, const float* __restrict__ T,
    _Float16* __restrict__ t_un, float* __restrict__ rowred) {
  const int row = blockIdx.x * 4 + (threadIdx.x >> 6);
  const int lane = threadIdx.x & 63;

  f16x8 mv8 = *(const f16x8*)(ma + (size_t)row * SS + lane * 8);
  float m[8];
#pragma unroll
  for (int e = 0; e < 8; ++e) m[e] = (float)mv8[e];

  float sma = 0.f, sma2 = 0.f, mabs = 0.f;
#pragma unroll
  for (int e = 0; e < 8; ++e) {
    sma += m[e];
    sma2 += m[e] * m[e];
    mabs = fmaxf(mabs, fabsf(m[e]));
  }
  sma = waveRedSum(sma);
  sma2 = waveRedSum(sma2);
  mabs = waveRedMax(mabs);

  float ex[8], esum = 0.f;
#pragma unroll
  for (int e = 0; e < 8; ++e) {
    ex[e] = __expf(clampf(m[e], -10.f, 10.f));
    esum += ex[e];
  }
  esum = waveRedSum(esum);
  float inv = 1.0f / esum;
  float Hv[8], sH = 0.f;
#pragma unroll
  for (int e = 0; e < 8; ++e) {
    float pp = ex[e] * inv;
    Hv[e] = -pp * __logf(pp + 1e-6f);
    sH += Hv[e];
  }
  sH = waveRedSum(sH);

  float fx[8], fsum = 0.f;
#pragma unroll
  for (int e = 0; e < 8; ++e) {
    fx[e] = __expf(3.0f * Hv[e]);
    fsum += fx[e];
  }
  fsum = waveRedSum(fsum);
  float finv = 1.0f / fsum;

  float t[8], st = 0.f, st2 = 0.f;
#pragma unroll
  for (int e = 0; e < 8; ++e) {
    float sa = clampf(m[e], -8.f, 8.f) * 0.05f;
    float pos = (sa + 0.4f) * ((float)NTAB / 0.8f);
    int idx = (int)pos;
    idx = idx < 0 ? 0 : (idx > NTAB - 1 ? NTAB - 1 : idx);
    float frac = pos - (float)idx;
    float g0 = T[idx], g1 = T[idx + 1];
    float sig = g0 + (g1 - g0) * frac;
    t[e] = sig * fx[e] * finv;
    st += t[e];
    st2 += t[e] * t[e];
  }
  st = waveRedSum(st);
  st2 = waveRedSum(st2);
  {
    f16x8 tw;
#pragma unroll
    for (int e = 0; e < 8; ++e) tw[e] = (_Float16)t[e];
    *(f16x8*)(t_un + (size_t)row * SS + lane * 8) = tw;
  }
  if (lane == 0) {
    float* rp = rowred + (size_t)row * 8;
    rp[0] = sma; rp[1] = sma2; rp[2] = mabs;
    rp[3] = st;  rp[4] = st2;  rp[5] = sH;
  }
}

// ---------------------------------------------------------------------------
// K_consts: per-batch blend constants (hoisted out of k_av). 4 blocks x 256.
__global__ __launch_bounds__(256) void k_consts(
    const float* __restrict__ rowred, float* __restrict__ cvec) {
  const int b_ = blockIdx.x;
  const int tid = threadIdx.x;
  __shared__ float red[4];
  const float* r0 = rowred + ((size_t)b_ * SS + tid * 2) * 8;
  const float* r1 = r0 + 8;
  float sma = blockRedSum(r0[0] + r1[0], red);
  float sma2 = blockRedSum(r0[1] + r1[1], red);
  float mabs = blockRedMax(fmaxf(r0[2], r1[2]), red);
  float st = blockRedSum(r0[3] + r1[3], red);
  float st2 = blockRedSum(r0[4] + r1[4], red);
  float sH = blockRedSum(r0[5] + r1[5], red);
  if (tid == 0) {
    const float N = (float)(SS * SS);
    float eo = sqrtf(sma2) + 1e-4f;
    float et = sqrtf(st2) + 1e-4f;
    float r = clampf(eo / et, 0.8f, 1.2f);
    float tmean = r * st / N;
    float om = sma / N;
    float vart = r * r * fmaxf(st2 / N - (st / N) * (st / N), 0.f);
    float tstd = sqrtf(fmaxf(vart, 0.01f));
    float varo = fmaxf(sma2 / N - om * om, 0.f);
    float ostd = sqrtf(fmaxf(varo, 0.01f));
    float gd = clampf(ostd / tstd, 0.8f, 1.2f);
    float ar = clampf(mabs, 1.f, 10.f);
    float sm = clampf(0.3f / log1pf(ar), 0.1f, 0.5f);
    float ent = sH / N;
    float ne = ent / logf((float)SS);
    float rr = 0.4f * (1.f - clampf(ne, 0.f, 0.4f));
    float G = sm * gd;
    cvec[b_ * 4 + 0] = rr * (1.f - G) * tmean;
    cvec[b_ * 4 + 1] = rr * G * r;
    cvec[b_ * 4 + 2] = rr;
  }
}

// ---------------------------------------------------------------------------
// K_av_fused v3: BARRIER-FREE main loop. Block = 16 rows x 1 head, 4 waves;
// wave w owns cols [w*128, w*128+128) of the key range with a PRIVATE LDS
// P-buffer (only intra-wave LDS deps -> compiler lgkmcnt, no __syncthreads).
// Grid (32 m, 32 bh) = 1024 blocks, 4/CU, 16 waves/CU, waves fully slip.
// End: one barrier; 4 col-partials (oacc, Z linear) combined via LDS,
// normalized f16 oh written coalesced.
__global__ __launch_bounds__(256) void k_av_fused(
    const _Float16* __restrict__ qh,
    const _Float16* __restrict__ kh, const _Float16* __restrict__ kl,
    const _Float16* __restrict__ ma, const _Float16* __restrict__ t_un,
    const float* __restrict__ cvec, const float* __restrict__ tau,
    const _Float16* __restrict__ vth, const _Float16* __restrict__ vtl,
    _Float16* __restrict__ oh) {
  const int bh = blockIdx.y;
  const int b_ = bh >> 3, hh = bh & 7;
  const int m0 = blockIdx.x * 16;
  const int tid = threadIdx.x;
  const int wave = tid >> 6, lane = tid & 63;
  const int quad = lane >> 4, l16 = lane & 15;
  const int cbeg = wave * 128;  // wave-private col range

  const float c0 = cvec[b_ * 4 + 0];
  const float c1 = cvec[b_ * 4 + 1];
  const float c2 = cvec[b_ * 4 + 2];
  const float itau = 1.0f / tau[0];

  __shared__ __align__(16) _Float16 Ph[4][16][40];  // wave-private P tiles
  __shared__ __align__(16) float Olds[4][16][68];   // end-combine partials
  __shared__ float Zlds[4][16];

  // Q fragments (A operand, high only): lane l16 = q-row
  const size_t qbase = (size_t)(b_ * SS + m0 + l16) * EE + hh * HD;
  f16x8 a_hi[2];
#pragma unroll
  for (int ks = 0; ks < 2; ++ks)
    a_hi[ks] = *(const f16x8*)(qh + qbase + ks * 32 + quad * 8);

  const size_t kbase = (size_t)b_ * SS * EE + hh * HD;
  const size_t vbase = ((size_t)bh * HD + l16) * SS;  // + dt*16*SS + col
  const size_t mrow = (size_t)(b_ * SS + m0 + quad * 4) * SS;  // + r*SS + col

  float z[4] = {0.f, 0.f, 0.f, 0.f};
  f32x4 oacc[4] = {};
  for (int c0i = cbeg; c0i < cbeg + 128; c0i += 32) {
    // K frags for 2 col-tiles (2-term h/l)
    f16x8 kbh[2][2], kbl[2][2];
#pragma unroll
    for (int ct = 0; ct < 2; ++ct) {
      const size_t kr = kbase + (size_t)(c0i + ct * 16 + l16) * EE;
#pragma unroll
      for (int ks = 0; ks < 2; ++ks) {
        kbh[ct][ks] = *(const f16x8*)(kh + kr + ks * 32 + quad * 8);
        kbl[ct][ks] = *(const f16x8*)(kl + kr + ks * 32 + quad * 8);
      }
    }
    // V frags for 4 d-tiles (k-slice = this 32-col chunk)
    f16x8 vbh[4], vbl[4];
#pragma unroll
    for (int dt = 0; dt < 4; ++dt) {
      const size_t vr = vbase + (size_t)(dt * 16) * SS + c0i + quad * 8;
      vbh[dt] = *(const f16x8*)(vth + vr);
      vbl[dt] = *(const f16x8*)(vtl + vr);
    }
    // ma/t values in C-layout (row = quad*4+r, col = ct*16+l16)
    _Float16 mv[2][4], tv[2][4];
#pragma unroll
    for (int ct = 0; ct < 2; ++ct)
#pragma unroll
      for (int r = 0; r < 4; ++r) {
        const size_t off = mrow + (size_t)r * SS + c0i + ct * 16 + l16;
        mv[ct][r] = ma[off];
        tv[ct][r] = t_un[off];
      }
    // QK + blend + exp -> wave-private P
#pragma unroll
    for (int ct = 0; ct < 2; ++ct) {
      f32x4 qacc = {};
#pragma unroll
      for (int ks = 0; ks < 2; ++ks) {
        qacc = __builtin_amdgcn_mfma_f32_16x16x32_f16(a_hi[ks], kbh[ct][ks], qacc, 0, 0, 0);
        qacc = __builtin_amdgcn_mfma_f32_16x16x32_f16(a_hi[ks], kbl[ct][ks], qacc, 0, 0, 0);
      }
#pragma unroll
      for (int r = 0; r < 4; ++r) {
        float sc = clampf(qacc[r], -15.f, 15.f);
        float v = (sc + c0 + c1 * (float)tv[ct][r] - c2 * (float)mv[ct][r]) * itau;
        float e = __expf(v) * 1.52587890625e-05f;  // * 2^-16
        z[r] += e;
        Ph[wave][quad * 4 + r][ct * 16 + l16] = (_Float16)e;
      }
    }
    // PV: A = P rows (l16), k = quad*8 within the 32-chunk
    f16x8 pa = *(const f16x8*)&Ph[wave][l16][quad * 8];
#pragma unroll
    for (int dt = 0; dt < 4; ++dt) {
      oacc[dt] = __builtin_amdgcn_mfma_f32_16x16x32_f16(pa, vbh[dt], oacc[dt], 0, 0, 0);
      oacc[dt] = __builtin_amdgcn_mfma_f32_16x16x32_f16(pa, vbl[dt], oacc[dt], 0, 0, 0);
    }
  }
  // wave-local Z reduce over the 16 l16 lanes (rows = quad*4+r preserved)
#pragma unroll
  for (int off = 1; off < 16; off <<= 1) {
#pragma unroll
    for (int r = 0; r < 4; ++r) z[r] += __shfl_xor(z[r], off);
  }
  if (l16 == 0) {
#pragma unroll
    for (int r = 0; r < 4; ++r) Zlds[wave][quad * 4 + r] = z[r];
  }
  // dump partial oacc: row = quad*4+r, d = dt*16+l16
#pragma unroll
  for (int dt = 0; dt < 4; ++dt)
#pragma unroll
    for (int r = 0; r < 4; ++r)
      Olds[wave][quad * 4 + r][dt * 16 + l16] = oacc[dt][r];
  __syncthreads();
  // combine 4 col-partials, normalize, write coalesced f16
  {
    const int row = tid >> 4;
    const int d0 = (tid & 15) * 4;
    float4 s0 = *(const float4*)&Olds[0][row][d0];
    float4 s1 = *(const float4*)&Olds[1][row][d0];
    float4 s2 = *(const float4*)&Olds[2][row][d0];
    float4 s3 = *(const float4*)&Olds[3][row][d0];
    float Z = Zlds[0][row] + Zlds[1][row] + Zlds[2][row] + Zlds[3][row];
    float rz = 1.0f / Z;
    _Float16* dst = oh + ((size_t)(b_ * SS + m0 + row)) * EE + hh * HD + d0;
    dst[0] = (_Float16)((s0.x + s1.x + s2.x + s3.x) * rz);
    dst[1] = (_Float16)((s0.y + s1.y + s2.y + s3.y) * rz);
    dst[2] = (_Float16)((s0.z + s1.z + s2.z + s3.z) * rz);
    dst[3] = (_Float16)((s0.w + s1.w + s2.w + s3.w) * rz);
  }
}

// ---------------------------------------------------------------------------
// K_out: 2-term f16 MFMA GEMM (oh*Wh + oh*Wl), fp32 output + bias.
__global__ __launch_bounds__(256) void k_out_mfma(
    const _Float16* __restrict__ oh,
    const _Float16* __restrict__ Wth, const _Float16* __restrict__ Wtl,
    const float* __restrict__ bo, float* __restrict__ out) {
  const int tid = threadIdx.x;
  const int wave = tid >> 6, lane = tid & 63;
  const int quad = lane >> 4, l16 = lane & 15;
  const int m0 = blockIdx.y * 64;
  const int n0 = blockIdx.x * 64;
  const _Float16* Bh = Wth + (size_t)3 * EE * EE;  // Wo^T
  const _Float16* Bl = Wtl + (size_t)3 * EE * EE;

  __shared__ _Float16 LAh[64][72], LBh[64][72], LBl[64][72];

  const int sr0 = tid >> 3, sc0 = (tid & 7) * 8;
  const int sr1 = sr0 + 32;

  f16x8 rA0h = *(const f16x8*)(oh + (size_t)(m0 + sr0) * EE + sc0);
  f16x8 rB0h = *(const f16x8*)(Bh + (size_t)(n0 + sr0) * EE + sc0);
  f16x8 rB0l = *(const f16x8*)(Bl + (size_t)(n0 + sr0) * EE + sc0);
  f16x8 rA1h = *(const f16x8*)(oh + (size_t)(m0 + sr1) * EE + sc0);
  f16x8 rB1h = *(const f16x8*)(Bh + (size_t)(n0 + sr1) * EE + sc0);
  f16x8 rB1l = *(const f16x8*)(Bl + (size_t)(n0 + sr1) * EE + sc0);

  f32x4 acc[4] = {};
  for (int k0 = 0; k0 < EE; k0 += 64) {
    if (k0) __syncthreads();
    *(f16x8*)&LAh[sr0][sc0] = rA0h;
    *(f16x8*)&LBh[sr0][sc0] = rB0h;
    *(f16x8*)&LBl[sr0][sc0] = rB0l;
    *(f16x8*)&LAh[sr1][sc0] = rA1h;
    *(f16x8*)&LBh[sr1][sc0] = rB1h;
    *(f16x8*)&LBl[sr1][sc0] = rB1l;
    __syncthreads();
    if (k0 + 64 < EE) {
      const int kn = k0 + 64;
      rA0h = *(const f16x8*)(oh + (size_t)(m0 + sr0) * EE + kn + sc0);
      rB0h = *(const f16x8*)(Bh + (size_t)(n0 + sr0) * EE + kn + sc0);
      rB0l = *(const f16x8*)(Bl + (size_t)(n0 + sr0) * EE + kn + sc0);
      rA1h = *(const f16x8*)(oh + (size_t)(m0 + sr1) * EE + kn + sc0);
      rB1h = *(const f16x8*)(Bh + (size_t)(n0 + sr1) * EE + kn + sc0);
      rB1l = *(const f16x8*)(Bl + (size_t)(n0 + sr1) * EE + kn + sc0);
    }
#pragma unroll
    for (int kk = 0; kk < 64; kk += 32) {
      f16x8 ah = *(const f16x8*)&LAh[wave * 16 + l16][kk + quad * 8];
#pragma unroll
      for (int nt = 0; nt < 4; ++nt) {
        f16x8 bhf = *(const f16x8*)&LBh[nt * 16 + l16][kk + quad * 8];
        f16x8 blf = *(const f16x8*)&LBl[nt * 16 + l16][kk + quad * 8];
        acc[nt] = __builtin_amdgcn_mfma_f32_16x16x32_f16(ah, bhf, acc[nt], 0, 0, 0);
        acc[nt] = __builtin_amdgcn_mfma_f32_16x16x32_f16(ah, blf, acc[nt], 0, 0, 0);
      }
    }
  }
  const int mbase = m0 + wave * 16 + quad * 4;
#pragma unroll
  for (int nt = 0; nt < 4; ++nt) {
    const int col = n0 + nt * 16 + l16;
    const float bb = bo[col];
#pragma unroll
    for (int r = 0; r < 4; ++r) {
      const int m = mbase + r;
      out[(size_t)m * EE + col] = acc[nt][r] + bb;
    }
  }
}

// ---------------------------------------------------------------------------
extern "C" void kernel_launch(void* const* d_in, const int* in_sizes, int n_in,
                              void* d_out, int out_size, void* d_ws,
                              size_t ws_size, hipStream_t stream) {
  const float* x = (const float*)d_in[0];
  const float* Wq = (const float*)d_in[1];
  const float* bq = (const float*)d_in[2];
  const float* Wk = (const float*)d_in[3];
  const float* bk = (const float*)d_in[4];
  const float* Wv = (const float*)d_in[5];
  const float* bv = (const float*)d_in[6];
  const float* Wo = (const float*)d_in[7];
  const float* bo = (const float*)d_in[8];
  const float* w1 = (const float*)d_in[9];
  const float* b1 = (const float*)d_in[10];
  const float* w2 = (const float*)d_in[11];
  const float* b2 = (const float*)d_in[12];
  const float* tau = (const float*)d_in[13];
  float* out = (float*)d_out;

  const size_t NX = (size_t)2048 * EE;           // 1M elems
  const size_t NW = (size_t)4 * EE * EE;         // 1M elems
  const size_t NQK = (size_t)BB * SS * EE;       // 1M elems
  const size_t NSS = (size_t)BB * SS * SS;       // 1M elems

  _Float16* Wth = (_Float16*)d_ws;
  _Float16* Wtl = Wth + NW;
  _Float16* xh = Wtl + NW;
  _Float16* qh = xh + NX;
  _Float16* kh = qh + NQK;
  _Float16* kl = kh + NQK;
  _Float16* vth = kl + NQK;
  _Float16* vtl = vth + NQK;
  _Float16* oh = vtl + NQK;
  _Float16* ma = oh + NX;
  _Float16* t_un = ma + NSS;
  float* T = (float*)(t_un + NSS);
  float* rowred = T + 8192;            // 2048*8
  float* cvec = rowred + 2048 * 8;     // 16

  k_prep<<<288, 256, 0, stream>>>(Wq, Wk, Wv, Wo, x, Wth, Wtl, xh);
  k_qkv_mfma<<<dim3(8, 32, 3), 256, 0, stream>>>(xh, Wth, Wtl, bq, bk, bv, w1,
                                                 b1, w2, b2, T, qh, kh, kl,
                                                 vth, vtl);
  k_ma_mfma<<<dim3(8, 32), 256, 0, stream>>>(qh, kh, kl, ma);
  k_rowstat<<<512, 256, 0, stream>>>(ma, T, t_un, rowred);
  k_consts<<<4, 256, 0, stream>>>(rowred, cvec);
  k_av_fused<<<dim3(32, 32), 256, 0, stream>>>(qh, kh, kl, ma, t_un, cvec,
                                               tau, vth, vtl, oh);
  k_out_mfma<<<dim3(8, 32), 256, 0, stream>>>(oh, Wth, Wtl, bo, out);
}

// Round 8
// 156.911 us; speedup vs baseline: 1.0709x; 1.0709x over previous
//
#include <hip/hip_runtime.h>
#include <math.h>

// Problem constants (fixed by setup_inputs)
#define BB 4
#define SS 512
#define EE 512
#define NH 8
#define HD 64
#define NC 128
#define NTAB 4096  // table intervals over sa in [-0.4, 0.4]

typedef _Float16 f16x8 __attribute__((ext_vector_type(8)));
typedef float f32x4 __attribute__((ext_vector_type(4)));

struct HL { _Float16 h, l; };

__device__ __forceinline__ float clampf(float v, float lo, float hi) {
  return fminf(fmaxf(v, lo), hi);
}
__device__ __forceinline__ HL split16(float x) {
  HL r;
  r.h = (_Float16)x;
  r.l = (_Float16)(x - (float)r.h);
  return r;
}

__device__ __forceinline__ float waveRedSum(float v) {
#pragma unroll
  for (int o = 32; o; o >>= 1) v += __shfl_xor(v, o);
  return v;
}
__device__ __forceinline__ float waveRedMax(float v) {
#pragma unroll
  for (int o = 32; o; o >>= 1) v = fmaxf(v, __shfl_xor(v, o));
  return v;
}
// blockDim.x == 256 (4 waves) assumed
__device__ __forceinline__ float blockRedSum(float v, float* red) {
  int tid = threadIdx.x;
  v = waveRedSum(v);
  __syncthreads();
  if ((tid & 63) == 0) red[tid >> 6] = v;
  __syncthreads();
  return red[0] + red[1] + red[2] + red[3];
}
__device__ __forceinline__ float blockRedMax(float v, float* red) {
  int tid = threadIdx.x;
  v = waveRedMax(v);
  __syncthreads();
  if ((tid & 63) == 0) red[tid >> 6] = v;
  __syncthreads();
  return fmaxf(fmaxf(red[0], red[1]), fmaxf(red[2], red[3]));
}

// ---------------------------------------------------------------------------
// K_prep: transpose+split the 4 weight matrices. 256 blocks.
// B-side keeps the full h/l split (the 2-term scheme is ah*(bh+bl)).
__global__ __launch_bounds__(256) void k_prep(
    const float* __restrict__ Wq, const float* __restrict__ Wk,
    const float* __restrict__ Wv, const float* __restrict__ Wo,
    _Float16* __restrict__ Wth, _Float16* __restrict__ Wtl) {
  const int j = blockIdx.x;         // [0,256)
  const int tid = threadIdx.x;
  const int z = j >> 6;             // matrix
  const int rem = j & 63;
  const int k0 = (rem & 7) * 64, n0 = (rem >> 3) * 64;
  const float* W = (z == 0) ? Wq : (z == 1) ? Wk : (z == 2) ? Wv : Wo;
  __shared__ float Tt[64][68];
  const int r = tid >> 2, c = (tid & 3) * 16;
#pragma unroll
  for (int jj = 0; jj < 16; jj += 4)
    *(float4*)&Tt[r][c + jj] =
        *(const float4*)(W + (size_t)(k0 + r) * EE + n0 + c + jj);
  __syncthreads();
  f16x8 h0, l0, h1, l1;
#pragma unroll
  for (int jj = 0; jj < 8; ++jj) {
    HL r0 = split16(Tt[c + jj][r]);
    HL r1 = split16(Tt[c + 8 + jj][r]);
    h0[jj] = r0.h; l0[jj] = r0.l;
    h1[jj] = r1.h; l1[jj] = r1.l;
  }
  _Float16* dh = Wth + ((size_t)z * EE + n0 + r) * EE + k0 + c;
  _Float16* dl = Wtl + ((size_t)z * EE + n0 + r) * EE + k0 + c;
  *(f16x8*)dh = h0;
  *(f16x8*)(dh + 8) = h1;
  *(f16x8*)dl = l0;
  *(f16x8*)(dl + 8) = l1;
}

// ---------------------------------------------------------------------------
// K_qkv: LDS-staged 2-term f16 MFMA GEMM (xh*Wh + xh*Wl; the dropped xl*Wh
// term is ~5e-5 RMS on q/k/v). A staged as f16-high only. q pre-scaled by
// 0.125. q/k stored in natural [B*S][E]; k keeps h/l split (consumed as
// B-operand downstream), q stores high only. V: transpose, split [bh][d][si].
__global__ __launch_bounds__(256) void k_qkv_mfma(
    const float* __restrict__ x,
    const _Float16* __restrict__ Wth, const _Float16* __restrict__ Wtl,
    const float* __restrict__ bq, const float* __restrict__ bk,
    const float* __restrict__ bv, const float* __restrict__ w1,
    const float* __restrict__ b1, const float* __restrict__ w2,
    const float* __restrict__ b2, float* __restrict__ T,
    _Float16* __restrict__ qh,
    _Float16* __restrict__ kh, _Float16* __restrict__ kl,
    _Float16* __restrict__ vth, _Float16* __restrict__ vtl) {
  const int which = blockIdx.z;
  const int tid = threadIdx.x;
  const int wave = tid >> 6, lane = tid & 63;
  const int quad = lane >> 4, l16 = lane & 15;
  const int m0 = blockIdx.y * 64;
  const int n0 = blockIdx.x * 64;
  const _Float16* Bh = Wth + (size_t)which * EE * EE;
  const _Float16* Bl = Wtl + (size_t)which * EE * EE;

  __shared__ __align__(16) char smpool[27648];
  _Float16(*LAh)[72] = (_Float16(*)[72])(smpool);
  _Float16(*LBh)[72] = (_Float16(*)[72])(smpool + 9216);
  _Float16(*LBl)[72] = (_Float16(*)[72])(smpool + 18432);
  float(*TR)[68] = (float(*)[68])(smpool);  // reused for V transpose

  const int sr0 = tid >> 3, sc0 = (tid & 7) * 8;
  const int sr1 = sr0 + 32;

  float4 rx0a = *(const float4*)(x + (size_t)(m0 + sr0) * EE + sc0);
  float4 rx0b = *(const float4*)(x + (size_t)(m0 + sr0) * EE + sc0 + 4);
  float4 rx1a = *(const float4*)(x + (size_t)(m0 + sr1) * EE + sc0);
  float4 rx1b = *(const float4*)(x + (size_t)(m0 + sr1) * EE + sc0 + 4);
  f16x8 rB0h = *(const f16x8*)(Bh + (size_t)(n0 + sr0) * EE + sc0);
  f16x8 rB0l = *(const f16x8*)(Bl + (size_t)(n0 + sr0) * EE + sc0);
  f16x8 rB1h = *(const f16x8*)(Bh + (size_t)(n0 + sr1) * EE + sc0);
  f16x8 rB1l = *(const f16x8*)(Bl + (size_t)(n0 + sr1) * EE + sc0);

  f32x4 acc[4] = {};
  for (int k0 = 0; k0 < EE; k0 += 64) {
    if (k0) __syncthreads();
    {
      float f0[8] = {rx0a.x, rx0a.y, rx0a.z, rx0a.w,
                     rx0b.x, rx0b.y, rx0b.z, rx0b.w};
      float f1[8] = {rx1a.x, rx1a.y, rx1a.z, rx1a.w,
                     rx1b.x, rx1b.y, rx1b.z, rx1b.w};
      f16x8 h0, h1;
#pragma unroll
      for (int j = 0; j < 8; ++j) {
        h0[j] = (_Float16)f0[j];
        h1[j] = (_Float16)f1[j];
      }
      *(f16x8*)&LAh[sr0][sc0] = h0;
      *(f16x8*)&LAh[sr1][sc0] = h1;
    }
    *(f16x8*)&LBh[sr0][sc0] = rB0h;
    *(f16x8*)&LBl[sr0][sc0] = rB0l;
    *(f16x8*)&LBh[sr1][sc0] = rB1h;
    *(f16x8*)&LBl[sr1][sc0] = rB1l;
    __syncthreads();
    if (k0 + 64 < EE) {
      const int kn = k0 + 64;
      rx0a = *(const float4*)(x + (size_t)(m0 + sr0) * EE + kn + sc0);
      rx0b = *(const float4*)(x + (size_t)(m0 + sr0) * EE + kn + sc0 + 4);
      rx1a = *(const float4*)(x + (size_t)(m0 + sr1) * EE + kn + sc0);
      rx1b = *(const float4*)(x + (size_t)(m0 + sr1) * EE + kn + sc0 + 4);
      rB0h = *(const f16x8*)(Bh + (size_t)(n0 + sr0) * EE + kn + sc0);
      rB0l = *(const f16x8*)(Bl + (size_t)(n0 + sr0) * EE + kn + sc0);
      rB1h = *(const f16x8*)(Bh + (size_t)(n0 + sr1) * EE + kn + sc0);
      rB1l = *(const f16x8*)(Bl + (size_t)(n0 + sr1) * EE + kn + sc0);
    }
#pragma unroll
    for (int kk = 0; kk < 64; kk += 32) {
      f16x8 ah = *(const f16x8*)&LAh[wave * 16 + l16][kk + quad * 8];
#pragma unroll
      for (int nt = 0; nt < 4; ++nt) {
        f16x8 bhf = *(const f16x8*)&LBh[nt * 16 + l16][kk + quad * 8];
        f16x8 blf = *(const f16x8*)&LBl[nt * 16 + l16][kk + quad * 8];
        acc[nt] = __builtin_amdgcn_mfma_f32_16x16x32_f16(ah, bhf, acc[nt], 0, 0, 0);
        acc[nt] = __builtin_amdgcn_mfma_f32_16x16x32_f16(ah, blf, acc[nt], 0, 0, 0);
      }
    }
  }
  const float* bias = (which == 0) ? bq : (which == 1) ? bk : bv;
  if (which == 2) {
    // V path: bias-add, transpose via LDS, store split-f16 [bh][d][si]
    __syncthreads();  // main-loop LDS reads done before overwrite
#pragma unroll
    for (int nt = 0; nt < 4; ++nt) {
      const int dcol = nt * 16 + l16;             // d within head
      const float bb = bias[n0 + nt * 16 + l16];  // n0 = head*64
#pragma unroll
      for (int r = 0; r < 4; ++r)
        TR[dcol][wave * 16 + quad * 4 + r] = acc[nt][r] + bb;
    }
    __syncthreads();
    const int d = tid >> 2, cc = (tid & 3) * 16;
    const int bh = (m0 >> 9) * NH + (n0 >> 6);
    const int si0 = m0 & 511;
    f16x8 h0, l0, h1, l1;
#pragma unroll
    for (int jj = 0; jj < 8; ++jj) {
      HL r0 = split16(TR[d][cc + jj]);
      HL r1 = split16(TR[d][cc + 8 + jj]);
      h0[jj] = r0.h; l0[jj] = r0.l;
      h1[jj] = r1.h; l1[jj] = r1.l;
    }
    _Float16* dh = vth + ((size_t)bh * HD + d) * SS + si0 + cc;
    _Float16* dl = vtl + ((size_t)bh * HD + d) * SS + si0 + cc;
    *(f16x8*)dh = h0;
    *(f16x8*)(dh + 8) = h1;
    *(f16x8*)dl = l0;
    *(f16x8*)(dl + 8) = l1;
  } else {
    // q path: high-only store (q-low never consumed downstream).
    // k path: h/l split store (k is a B-operand downstream).
    const float postscale = (which == 0) ? 0.125f : 1.0f;
    const int mbase = m0 + wave * 16 + quad * 4;
#pragma unroll
    for (int nt = 0; nt < 4; ++nt) {
      const int col = n0 + nt * 16 + l16;
      const float bb = bias[col];
#pragma unroll
      for (int r = 0; r < 4; ++r) {
        const size_t idx = (size_t)(mbase + r) * EE + col;
        const float val = (acc[nt][r] + bb) * postscale;
        if (which == 0) {
          qh[idx] = (_Float16)val;
        } else {
          HL sp = split16(val);
          kh[idx] = sp.h;
          kl[idx] = sp.l;
        }
      }
    }
    // sigmoid-table side job: 17 q-blocks tabulate T (used by k_rowstat)
    if (which == 0 && blockIdx.x == 0 && blockIdx.y < 17) {
      int idx = blockIdx.y * 256 + tid;
      if (idx <= NTAB) {
        float sa = -0.4f + (float)idx * (0.8f / (float)NTAB);
        float ap = 0.f;
#pragma unroll 4
        for (int c = 0; c < NC; ++c) {
          float h = fminf(fmaxf(sa * w1[c] + b1[c], 0.f), 5.f);
          ap += h * w2[c];
        }
        ap = clampf(ap + b2[0], -5.f, 5.f);
        float tay = clampf(1.0f + 0.05f * (ap * 50.0f), 0.5f, 1.5f);
        T[idx] = 1.0f / (1.0f + expf(-tay));
      }
    }
  }
}

// ---------------------------------------------------------------------------
// K_ma: head-mean of scores WITHOUT materializing s:
// ma = 0.125 * Q_flat @ K_flat^T (K=512). 2-term: qh*kh + qh*kl.
__global__ __launch_bounds__(256) void k_ma_mfma(
    const _Float16* __restrict__ qh,
    const _Float16* __restrict__ kh, const _Float16* __restrict__ kl,
    float* __restrict__ ma) {
  const int tid = threadIdx.x;
  const int wave = tid >> 6, lane = tid & 63;
  const int quad = lane >> 4, l16 = lane & 15;
  const int m0 = blockIdx.y * 64;
  const int n0 = blockIdx.x * 64;
  const _Float16* Bh = kh + (size_t)(m0 >> 9) * SS * EE;  // per-batch K base
  const _Float16* Bl = kl + (size_t)(m0 >> 9) * SS * EE;

  __shared__ _Float16 LAh[64][72], LBh[64][72], LBl[64][72];

  const int sr0 = tid >> 3, sc0 = (tid & 7) * 8;
  const int sr1 = sr0 + 32;

  f16x8 rA0h = *(const f16x8*)(qh + (size_t)(m0 + sr0) * EE + sc0);
  f16x8 rB0h = *(const f16x8*)(Bh + (size_t)(n0 + sr0) * EE + sc0);
  f16x8 rB0l = *(const f16x8*)(Bl + (size_t)(n0 + sr0) * EE + sc0);
  f16x8 rA1h = *(const f16x8*)(qh + (size_t)(m0 + sr1) * EE + sc0);
  f16x8 rB1h = *(const f16x8*)(Bh + (size_t)(n0 + sr1) * EE + sc0);
  f16x8 rB1l = *(const f16x8*)(Bl + (size_t)(n0 + sr1) * EE + sc0);

  f32x4 acc[4] = {};
  for (int k0 = 0; k0 < EE; k0 += 64) {
    if (k0) __syncthreads();
    *(f16x8*)&LAh[sr0][sc0] = rA0h;
    *(f16x8*)&LBh[sr0][sc0] = rB0h;
    *(f16x8*)&LBl[sr0][sc0] = rB0l;
    *(f16x8*)&LAh[sr1][sc0] = rA1h;
    *(f16x8*)&LBh[sr1][sc0] = rB1h;
    *(f16x8*)&LBl[sr1][sc0] = rB1l;
    __syncthreads();
    if (k0 + 64 < EE) {
      const int kn = k0 + 64;
      rA0h = *(const f16x8*)(qh + (size_t)(m0 + sr0) * EE + kn + sc0);
      rB0h = *(const f16x8*)(Bh + (size_t)(n0 + sr0) * EE + kn + sc0);
      rB0l = *(const f16x8*)(Bl + (size_t)(n0 + sr0) * EE + kn + sc0);
      rA1h = *(const f16x8*)(qh + (size_t)(m0 + sr1) * EE + kn + sc0);
      rB1h = *(const f16x8*)(Bh + (size_t)(n0 + sr1) * EE + kn + sc0);
      rB1l = *(const f16x8*)(Bl + (size_t)(n0 + sr1) * EE + kn + sc0);
    }
#pragma unroll
    for (int kk = 0; kk < 64; kk += 32) {
      f16x8 ah = *(const f16x8*)&LAh[wave * 16 + l16][kk + quad * 8];
#pragma unroll
      for (int nt = 0; nt < 4; ++nt) {
        f16x8 bhf = *(const f16x8*)&LBh[nt * 16 + l16][kk + quad * 8];
        f16x8 blf = *(const f16x8*)&LBl[nt * 16 + l16][kk + quad * 8];
        acc[nt] = __builtin_amdgcn_mfma_f32_16x16x32_f16(ah, bhf, acc[nt], 0, 0, 0);
        acc[nt] = __builtin_amdgcn_mfma_f32_16x16x32_f16(ah, blf, acc[nt], 0, 0, 0);
      }
    }
  }
  const int mbase = m0 + wave * 16 + quad * 4;
#pragma unroll
  for (int nt = 0; nt < 4; ++nt) {
    const int col = n0 + nt * 16 + l16;
#pragma unroll
    for (int r = 0; r < 4; ++r) {
      ma[(size_t)(mbase + r) * SS + col] = acc[nt][r] * 0.125f;
    }
  }
}

// ---------------------------------------------------------------------------
// K_rowstat: per-row autopoietic transform from ma. 512 blocks x 4 waves,
// one wave per row. HW exp/log (__expf/__logf): only delta vs the 158.1-µs
// R2 config — shortens the serial VALU chain in this latency-bound kernel.
__global__ __launch_bounds__(256) void k_rowstat(
    const float* __restrict__ ma, const float* __restrict__ T,
    float* __restrict__ t_un, float* __restrict__ rowred) {
  const int row = blockIdx.x * 4 + (threadIdx.x >> 6);  // b*S + i
  const int lane = threadIdx.x & 63;

  const float4* p =
      reinterpret_cast<const float4*>(ma + (size_t)row * SS) + lane * 2;
  float4 u0 = p[0], u1 = p[1];
  float m[8] = {u0.x, u0.y, u0.z, u0.w, u1.x, u1.y, u1.z, u1.w};

  float sma = 0.f, sma2 = 0.f, mabs = 0.f;
#pragma unroll
  for (int e = 0; e < 8; ++e) {
    sma += m[e];
    sma2 += m[e] * m[e];
    mabs = fmaxf(mabs, fabsf(m[e]));
  }
  sma = waveRedSum(sma);
  sma2 = waveRedSum(sma2);
  mabs = waveRedMax(mabs);

  float ex[8], esum = 0.f;
#pragma unroll
  for (int e = 0; e < 8; ++e) {
    ex[e] = __expf(clampf(m[e], -10.f, 10.f));
    esum += ex[e];
  }
  esum = waveRedSum(esum);
  float inv = 1.0f / esum;
  float Hv[8], sH = 0.f;
#pragma unroll
  for (int e = 0; e < 8; ++e) {
    float pp = ex[e] * inv;
    Hv[e] = -pp * __logf(pp + 1e-6f);
    sH += Hv[e];
  }
  sH = waveRedSum(sH);

  float fx[8], fsum = 0.f;
#pragma unroll
  for (int e = 0; e < 8; ++e) {
    fx[e] = __expf(3.0f * Hv[e]);
    fsum += fx[e];
  }
  fsum = waveRedSum(fsum);
  float finv = 1.0f / fsum;

  float t[8], st = 0.f, st2 = 0.f;
#pragma unroll
  for (int e = 0; e < 8; ++e) {
    float sa = clampf(m[e], -8.f, 8.f) * 0.05f;
    float pos = (sa + 0.4f) * ((float)NTAB / 0.8f);
    int idx = (int)pos;
    idx = idx < 0 ? 0 : (idx > NTAB - 1 ? NTAB - 1 : idx);
    float frac = pos - (float)idx;
    float g0 = T[idx], g1 = T[idx + 1];
    float sig = g0 + (g1 - g0) * frac;
    t[e] = sig * fx[e] * finv;
    st += t[e];
    st2 += t[e] * t[e];
  }
  st = waveRedSum(st);
  st2 = waveRedSum(st2);
  {
    float4* tp = reinterpret_cast<float4*>(t_un + (size_t)row * SS) + lane * 2;
    float4 w0 = {t[0], t[1], t[2], t[3]}, w1v = {t[4], t[5], t[6], t[7]};
    tp[0] = w0;
    tp[1] = w1v;
  }
  if (lane == 0) {
    float* rp = rowred + (size_t)row * 8;
    rp[0] = sma; rp[1] = sma2; rp[2] = mabs;
    rp[3] = st;  rp[4] = st2;  rp[5] = sH;
  }
}

// ---------------------------------------------------------------------------
// K_av_fused: out = softmax(blend(s)) @ v, s recomputed in-register.
// R2 structure (best measured): 32 rows x 1 head per block, grid (16,32),
// 256 threads, inline per-block consts. Only delta: __expf.
__global__ __launch_bounds__(256) void k_av_fused(
    const _Float16* __restrict__ qh,
    const _Float16* __restrict__ kh, const _Float16* __restrict__ kl,
    const float* __restrict__ ma, const float* __restrict__ t_un,
    const float* __restrict__ rowred, const float* __restrict__ tau,
    const _Float16* __restrict__ vth, const _Float16* __restrict__ vtl,
    _Float16* __restrict__ oh) {
  const int bh = blockIdx.y;
  const int b_ = bh >> 3, hh = bh & 7;
  const int m0 = blockIdx.x * 32;
  const int tid = threadIdx.x;
  const int wave = tid >> 6, lane = tid & 63;
  const int quad = lane >> 4, l16 = lane & 15;
  const int mt = wave >> 1, nt = wave & 1;

  __shared__ float red[4];
  // ---- per-batch blend constants (redundant per block; 16 KB L2-hot read)
  float c0, c1, c2;
  {
    const float* r0 = rowred + ((size_t)b_ * SS + tid * 2) * 8;
    const float* r1 = r0 + 8;
    float sma = blockRedSum(r0[0] + r1[0], red);
    float sma2 = blockRedSum(r0[1] + r1[1], red);
    float mabs = blockRedMax(fmaxf(r0[2], r1[2]), red);
    float st = blockRedSum(r0[3] + r1[3], red);
    float st2 = blockRedSum(r0[4] + r1[4], red);
    float sH = blockRedSum(r0[5] + r1[5], red);
    const float N = (float)(SS * SS);
    float eo = sqrtf(sma2) + 1e-4f;
    float et = sqrtf(st2) + 1e-4f;
    float r = clampf(eo / et, 0.8f, 1.2f);
    float tmean = r * st / N;
    float om = sma / N;
    float vart = r * r * fmaxf(st2 / N - (st / N) * (st / N), 0.f);
    float tstd = sqrtf(fmaxf(vart, 0.01f));
    float varo = fmaxf(sma2 / N - om * om, 0.f);
    float ostd = sqrtf(fmaxf(varo, 0.01f));
    float gd = clampf(ostd / tstd, 0.8f, 1.2f);
    float ar = clampf(mabs, 1.f, 10.f);
    float sm = clampf(0.3f / log1pf(ar), 0.1f, 0.5f);
    float ent = sH / N;
    float ne = ent / logf((float)SS);
    float rr = 0.4f * (1.f - clampf(ne, 0.f, 0.4f));
    float G = sm * gd;
    c0 = rr * (1.f - G) * tmean;
    c1 = rr * G * r;
    c2 = rr;
  }
  const float itau = 1.0f / tau[0];

  __shared__ _Float16 Ph[32][40];
  __shared__ float Zp[32][2];

  // Q fragments (A operand, high only), fixed for the whole block
  const size_t qbase = (size_t)(b_ * SS + m0 + mt * 16 + l16) * EE + hh * HD;
  f16x8 a_hi[2];
#pragma unroll
  for (int ks = 0; ks < 2; ++ks)
    a_hi[ks] = *(const f16x8*)(qh + qbase + ks * 32 + quad * 8);

  const size_t kbase = (size_t)b_ * SS * EE + hh * HD;
  const size_t vbase = ((size_t)bh * HD + wave * 16 + l16) * SS;
  const size_t mb0 =
      (size_t)(b_ * SS + m0 + mt * 16 + quad * 4) * SS + nt * 16 + l16;

  // preload iter 0
  f16x8 kb_h[2], kb_l[2], vb_h, vb_l;
  float mv[4], tv[4];
  {
    const size_t kr = kbase + (size_t)(nt * 16 + l16) * EE;
#pragma unroll
    for (int ks = 0; ks < 2; ++ks) {
      kb_h[ks] = *(const f16x8*)(kh + kr + ks * 32 + quad * 8);
      kb_l[ks] = *(const f16x8*)(kl + kr + ks * 32 + quad * 8);
    }
    vb_h = *(const f16x8*)(vth + vbase + quad * 8);
    vb_l = *(const f16x8*)(vtl + vbase + quad * 8);
#pragma unroll
    for (int r = 0; r < 4; ++r) {
      mv[r] = ma[mb0 + (size_t)r * SS];
      tv[r] = t_un[mb0 + (size_t)r * SS];
    }
  }

  float z[4] = {0.f, 0.f, 0.f, 0.f};
  f32x4 oacc[2] = {};
  for (int k0 = 0; k0 < SS; k0 += 32) {
    // QK quadrant: rows mt*16+.., cols k0+nt*16+..  (2-term)
    f32x4 qacc = {};
#pragma unroll
    for (int ks = 0; ks < 2; ++ks) {
      qacc = __builtin_amdgcn_mfma_f32_16x16x32_f16(a_hi[ks], kb_h[ks], qacc, 0, 0, 0);
      qacc = __builtin_amdgcn_mfma_f32_16x16x32_f16(a_hi[ks], kb_l[ks], qacc, 0, 0, 0);
    }
    const f16x8 vh_c = vb_h, vl_c = vb_l;  // current-iter V frags
    __syncthreads();  // previous PV done reading Ph
    // blend + exp in MFMA C-layout, write f16 P
#pragma unroll
    for (int r = 0; r < 4; ++r) {
      float sc = clampf(qacc[r], -15.f, 15.f);
      float v = (sc + c0 + c1 * tv[r] - c2 * mv[r]) * itau;
      float e = __expf(v) * 1.52587890625e-05f;  // * 2^-16
      z[r] += e;
      Ph[mt * 16 + quad * 4 + r][nt * 16 + l16] = (_Float16)e;
    }
    // prefetch next iter's K frags, V frags, ma/t values
    if (k0 + 32 < SS) {
      const int kn = k0 + 32;
      const size_t kr = kbase + (size_t)(kn + nt * 16 + l16) * EE;
#pragma unroll
      for (int ks = 0; ks < 2; ++ks) {
        kb_h[ks] = *(const f16x8*)(kh + kr + ks * 32 + quad * 8);
        kb_l[ks] = *(const f16x8*)(kl + kr + ks * 32 + quad * 8);
      }
      vb_h = *(const f16x8*)(vth + vbase + kn + quad * 8);
      vb_l = *(const f16x8*)(vtl + vbase + kn + quad * 8);
#pragma unroll
      for (int r = 0; r < 4; ++r) {
        mv[r] = ma[mb0 + (size_t)r * SS + kn];
        tv[r] = t_un[mb0 + (size_t)r * SS + kn];
      }
    }
    __syncthreads();  // Ph ready
#pragma unroll
    for (int mt2 = 0; mt2 < 2; ++mt2) {
      f16x8 ah = *(const f16x8*)&Ph[mt2 * 16 + l16][quad * 8];
      oacc[mt2] = __builtin_amdgcn_mfma_f32_16x16x32_f16(ah, vh_c, oacc[mt2], 0, 0, 0);
      oacc[mt2] = __builtin_amdgcn_mfma_f32_16x16x32_f16(ah, vl_c, oacc[mt2], 0, 0, 0);
    }
  }
  // Z: reduce per-lane partials over the 16 l16 lanes (same 4 rows)
#pragma unroll
  for (int off = 1; off < 16; off <<= 1) {
#pragma unroll
    for (int r = 0; r < 4; ++r) z[r] += __shfl_xor(z[r], off);
  }
  if (l16 == 0) {
#pragma unroll
    for (int r = 0; r < 4; ++r) Zp[mt * 16 + quad * 4 + r][nt] = z[r];
  }
  __syncthreads();
#pragma unroll
  for (int mt2 = 0; mt2 < 2; ++mt2) {
#pragma unroll
    for (int r = 0; r < 4; ++r) {
      const int lr = mt2 * 16 + quad * 4 + r;  // local row 0..31
      const float Z = Zp[lr][0] + Zp[lr][1];
      const float oV = oacc[mt2][r] / Z;
      const int si = m0 + lr;
      const size_t idx =
          ((size_t)(b_ * SS + si)) * EE + hh * HD + wave * 16 + l16;
      oh[idx] = (_Float16)oV;
    }
  }
}

// ---------------------------------------------------------------------------
// K_out: 2-term f16 MFMA GEMM (oh*Wh + oh*Wl), fp32 output + bias.
__global__ __launch_bounds__(256) void k_out_mfma(
    const _Float16* __restrict__ oh,
    const _Float16* __restrict__ Wth, const _Float16* __restrict__ Wtl,
    const float* __restrict__ bo, float* __restrict__ out) {
  const int tid = threadIdx.x;
  const int wave = tid >> 6, lane = tid & 63;
  const int quad = lane >> 4, l16 = lane & 15;
  const int m0 = blockIdx.y * 64;
  const int n0 = blockIdx.x * 64;
  const _Float16* Bh = Wth + (size_t)3 * EE * EE;  // Wo^T
  const _Float16* Bl = Wtl + (size_t)3 * EE * EE;

  __shared__ _Float16 LAh[64][72], LBh[64][72], LBl[64][72];

  const int sr0 = tid >> 3, sc0 = (tid & 7) * 8;
  const int sr1 = sr0 + 32;

  f16x8 rA0h = *(const f16x8*)(oh + (size_t)(m0 + sr0) * EE + sc0);
  f16x8 rB0h = *(const f16x8*)(Bh + (size_t)(n0 + sr0) * EE + sc0);
  f16x8 rB0l = *(const f16x8*)(Bl + (size_t)(n0 + sr0) * EE + sc0);
  f16x8 rA1h = *(const f16x8*)(oh + (size_t)(m0 + sr1) * EE + sc0);
  f16x8 rB1h = *(const f16x8*)(Bh + (size_t)(n0 + sr1) * EE + sc0);
  f16x8 rB1l = *(const f16x8*)(Bl + (size_t)(n0 + sr1) * EE + sc0);

  f32x4 acc[4] = {};
  for (int k0 = 0; k0 < EE; k0 += 64) {
    if (k0) __syncthreads();
    *(f16x8*)&LAh[sr0][sc0] = rA0h;
    *(f16x8*)&LBh[sr0][sc0] = rB0h;
    *(f16x8*)&LBl[sr0][sc0] = rB0l;
    *(f16x8*)&LAh[sr1][sc0] = rA1h;
    *(f16x8*)&LBh[sr1][sc0] = rB1h;
    *(f16x8*)&LBl[sr1][sc0] = rB1l;
    __syncthreads();
    if (k0 + 64 < EE) {
      const int kn = k0 + 64;
      rA0h = *(const f16x8*)(oh + (size_t)(m0 + sr0) * EE + kn + sc0);
      rB0h = *(const f16x8*)(Bh + (size_t)(n0 + sr0) * EE + kn + sc0);
      rB0l = *(const f16x8*)(Bl + (size_t)(n0 + sr0) * EE + kn + sc0);
      rA1h = *(const f16x8*)(oh + (size_t)(m0 + sr1) * EE + kn + sc0);
      rB1h = *(const f16x8*)(Bh + (size_t)(n0 + sr1) * EE + kn + sc0);
      rB1l = *(const f16x8*)(Bl + (size_t)(n0 + sr1) * EE + kn + sc0);
    }
#pragma unroll
    for (int kk = 0; kk < 64; kk += 32) {
      f16x8 ah = *(const f16x8*)&LAh[wave * 16 + l16][kk + quad * 8];
#pragma unroll
      for (int nt = 0; nt < 4; ++nt) {
        f16x8 bhf = *(const f16x8*)&LBh[nt * 16 + l16][kk + quad * 8];
        f16x8 blf = *(const f16x8*)&LBl[nt * 16 + l16][kk + quad * 8];
        acc[nt] = __builtin_amdgcn_mfma_f32_16x16x32_f16(ah, bhf, acc[nt], 0, 0, 0);
        acc[nt] = __builtin_amdgcn_mfma_f32_16x16x32_f16(ah, blf, acc[nt], 0, 0, 0);
      }
    }
  }
  const int mbase = m0 + wave * 16 + quad * 4;
#pragma unroll
  for (int nt = 0; nt < 4; ++nt) {
    const int col = n0 + nt * 16 + l16;
    const float bb = bo[col];
#pragma unroll
    for (int r = 0; r < 4; ++r) {
      const int m = mbase + r;
      out[(size_t)m * EE + col] = acc[nt][r] + bb;
    }
  }
}

// ---------------------------------------------------------------------------
extern "C" void kernel_launch(void* const* d_in, const int* in_sizes, int n_in,
                              void* d_out, int out_size, void* d_ws,
                              size_t ws_size, hipStream_t stream) {
  const float* x = (const float*)d_in[0];
  const float* Wq = (const float*)d_in[1];
  const float* bq = (const float*)d_in[2];
  const float* Wk = (const float*)d_in[3];
  const float* bk = (const float*)d_in[4];
  const float* Wv = (const float*)d_in[5];
  const float* bv = (const float*)d_in[6];
  const float* Wo = (const float*)d_in[7];
  const float* bo = (const float*)d_in[8];
  const float* w1 = (const float*)d_in[9];
  const float* b1 = (const float*)d_in[10];
  const float* w2 = (const float*)d_in[11];
  const float* b2 = (const float*)d_in[12];
  const float* tau = (const float*)d_in[13];
  float* out = (float*)d_out;

  const size_t NX = (size_t)2048 * EE;           // 1M elems (o)
  const size_t NW = (size_t)4 * EE * EE;         // 1M elems (4 W's)
  const size_t NQK = (size_t)BB * SS * EE;       // 1M elems

  _Float16* Wth = (_Float16*)d_ws;
  _Float16* Wtl = Wth + NW;
  _Float16* qh = Wtl + NW;
  _Float16* kh = qh + NQK;
  _Float16* kl = kh + NQK;
  _Float16* vth = kl + NQK;
  _Float16* vtl = vth + NQK;
  _Float16* oh = vtl + NQK;
  float* ma = (float*)(oh + NX);
  float* t_un = ma + (size_t)BB * SS * SS;
  float* T = t_un + (size_t)BB * SS * SS;
  float* rowred = T + 8192;            // 2048*8

  k_prep<<<256, 256, 0, stream>>>(Wq, Wk, Wv, Wo, Wth, Wtl);
  k_qkv_mfma<<<dim3(8, 32, 3), 256, 0, stream>>>(x, Wth, Wtl, bq, bk, bv, w1,
                                                 b1, w2, b2, T, qh, kh, kl,
                                                 vth, vtl);
  k_ma_mfma<<<dim3(8, 32), 256, 0, stream>>>(qh, kh, kl, ma);
  k_rowstat<<<512, 256, 0, stream>>>(ma, T, t_un, rowred);
  k_av_fused<<<dim3(16, 32), 256, 0, stream>>>(qh, kh, kl, ma, t_un,
                                               rowred, tau, vth, vtl, oh);
  k_out_mfma<<<dim3(8, 32), 256, 0, stream>>>(oh, Wth, Wtl, bo, out);
}